// Round 8
// baseline (421.953 us; speedup 1.0000x reference)
//
#include <hip/hip_runtime.h>
#include <hip/hip_bf16.h>

constexpr int DIN = 16;
constexpr int D   = 256;
constexpr int NH  = 8;
constexpr int NC  = 32;
constexpr int MC  = 200;
constexpr int NT  = 8;
constexpr int BG  = 16;
constexpr int NL  = 6;
constexpr int PS  = 16;   // pool slices per graph
constexpr float NEG = 0.2f;

typedef __attribute__((ext_vector_type(8))) short bfrag;
typedef __attribute__((ext_vector_type(4))) float f32x4;

__device__ inline unsigned short f2bf(float f) {
    unsigned int u = __float_as_uint(f);
    u += 0x7FFFu + ((u >> 16) & 1u);
    return (unsigned short)(u >> 16);
}
__device__ inline float bf2f(unsigned short u) {
    return __uint_as_float((unsigned int)u << 16);
}

__device__ inline float dot_ilp(const float* g, const float* __restrict__ W, int K, int ldw, int t) {
    float a0 = 0.f, a1 = 0.f, a2 = 0.f, a3 = 0.f;
    for (int k = 0; k < K; k += 4) {
        a0 = fmaf(g[k + 0], W[(k + 0) * ldw + t], a0);
        a1 = fmaf(g[k + 1], W[(k + 1) * ldw + t], a1);
        a2 = fmaf(g[k + 2], W[(k + 2) * ldw + t], a2);
        a3 = fmaf(g[k + 3], W[(k + 3) * ldw + t], a3);
    }
    return (a0 + a1) + (a2 + a3);
}

// ---------------- device helpers ----------------

__device__ inline void enc_node(const float* x, const float* W, const float* b, const float* ls,
                                const float* lb, float* h, int n, int lane) {
    int c4 = lane * 4;
    float xs[DIN];
#pragma unroll
    for (int k = 0; k < DIN; k += 4) {
        float4 xv = *(const float4*)&x[n * DIN + k];
        xs[k] = xv.x; xs[k + 1] = xv.y; xs[k + 2] = xv.z; xs[k + 3] = xv.w;
    }
    float4 a = *(const float4*)&b[c4];
#pragma unroll
    for (int k = 0; k < DIN; k++) {
        float4 wv = *(const float4*)&W[k * D + c4];
        a.x = fmaf(xs[k], wv.x, a.x);
        a.y = fmaf(xs[k], wv.y, a.y);
        a.z = fmaf(xs[k], wv.z, a.z);
        a.w = fmaf(xs[k], wv.w, a.w);
    }
    float s = a.x + a.y + a.z + a.w;
#pragma unroll
    for (int msk = 1; msk <= 32; msk <<= 1) s += __shfl_xor(s, msk);
    float mu = s * (1.f / D);
    float4 dv = make_float4(a.x - mu, a.y - mu, a.z - mu, a.w - mu);
    float v2 = dv.x * dv.x + dv.y * dv.y + dv.z * dv.z + dv.w * dv.w;
#pragma unroll
    for (int msk = 1; msk <= 32; msk <<= 1) v2 += __shfl_xor(v2, msk);
    float rstd = rsqrtf(v2 * (1.f / D) + 1e-5f);
    float4 lsv = *(const float4*)&ls[c4];
    float4 lbv = *(const float4*)&lb[c4];
    float4 y = make_float4(fmaxf(dv.x * rstd * lsv.x + lbv.x, 0.f),
                           fmaxf(dv.y * rstd * lsv.y + lbv.y, 0.f),
                           fmaxf(dv.z * rstd * lsv.z + lbv.z, 0.f),
                           fmaxf(dv.w * rstd * lsv.w + lbv.w, 0.f));
    *(float4*)&h[(size_t)n * D + c4] = y;
}

// MFMA GEMM on a 16-row tile, one wave handles one 16-col tile (ctg).
__device__ inline void gemm_one_ct(const unsigned short (*As)[264],
                                   const unsigned short* WpL, const unsigned short* WpR,
                                   const float* bl, const float* br,
                                   unsigned short* xl, unsigned short* xr,
                                   int N, int nb, int ctg, int lane) {
    int m = lane & 15, q = lane >> 4;
    float bLv = bl[ctg * 16 + m];
    float bRv = br[ctg * 16 + m];
    f32x4 accL = (f32x4){bLv, bLv, bLv, bLv};
    f32x4 accR = (f32x4){bRv, bRv, bRv, bRv};
#pragma unroll
    for (int ks = 0; ks < 8; ks++) {
        bfrag af = *(const bfrag*)&As[m][ks * 32 + q * 8];
        size_t off = (((size_t)ctg * 8 + ks) * 64 + lane) * 8;
        bfrag bL = *(const bfrag*)&WpL[off];
        bfrag bR = *(const bfrag*)&WpR[off];
        accL = __builtin_amdgcn_mfma_f32_16x16x32_bf16(af, bL, accL, 0, 0, 0);
        accR = __builtin_amdgcn_mfma_f32_16x16x32_bf16(af, bR, accR, 0, 0, 0);
    }
    int colg = ctg * 16 + m;
#pragma unroll
    for (int reg = 0; reg < 4; reg++) {
        int row = nb + q * 4 + reg;
        if (row < N) {
            xl[(size_t)row * D + colg] = f2bf(accL[reg]);
            xr[(size_t)row * D + colg] = f2bf(accR[reg]);
        }
    }
}

// 4-wave variant (wave w owns col-tiles w*4..w*4+3)
__device__ inline void gemm_core(const unsigned short (*As)[264],
                                 const unsigned short* WpL, const unsigned short* WpR,
                                 const float* bl, const float* br,
                                 unsigned short* xl, unsigned short* xr, int N, int nb, int T) {
    int lane = T & 63, w = T >> 6;
#pragma unroll
    for (int ct = 0; ct < 4; ct++)
        gemm_one_ct(As, WpL, WpR, bl, br, xl, xr, N, nb, w * 4 + ct, lane);
}

__device__ inline void repack_attn_one(const float* Wl, const float* Wr, unsigned short* Wp, int tid) {
    int lane = tid & 63;
    int r1 = tid >> 6;
    int ks = r1 & 7;
    int r2 = r1 >> 3;
    int ct = r2 & 15;
    int mi = r2 >> 4;
    int layer = mi >> 1, mat = mi & 1;
    const float* W = (mat == 0 ? Wl : Wr) + (size_t)layer * D * D;
    int n = ct * 16 + (lane & 15);
    int kb = ks * 32 + (lane >> 4) * 8;
    size_t base = (((size_t)(mi * 16 + ct) * 8 + ks) * 64 + lane) * 8;
#pragma unroll
    for (int j = 0; j < 8; j++) Wp[base + j] = f2bf(W[(size_t)(kb + j) * D + n]);
}

__device__ inline void repack_gen_one(const float* W, unsigned short* Wp, int K, int NCOL, int nks, int tid) {
    int lane = tid & 63;
    int r = tid >> 6;
    int ks = r % nks;
    int ct = r / nks;
    int n = ct * 16 + (lane & 15);
    int kb = ks * 32 + (lane >> 4) * 8;
    size_t base = (((size_t)ct * nks + ks) * 64 + lane) * 8;
#pragma unroll
    for (int j = 0; j < 8; j++) {
        int k = kb + j;
        Wp[base + j] = (n < NCOL && k < K) ? f2bf(W[(size_t)k * NCOL + n]) : (unsigned short)0;
    }
}

// ---------------- kernels ----------------

// encoder + edge count (deg pre-zeroed) + all weight repacks, fused.
__global__ __launch_bounds__(256) void fused_init_k(const float* __restrict__ x, const float* __restrict__ encW,
                                                    const float* __restrict__ encb, const float* __restrict__ encls,
                                                    const float* __restrict__ enclb, float* __restrict__ h, int N,
                                                    const int* __restrict__ dst, int* __restrict__ deg, int E,
                                                    const float* __restrict__ Wl, const float* __restrict__ Wr,
                                                    unsigned short* __restrict__ Wp,
                                                    const float* __restrict__ cW1, unsigned short* __restrict__ cW1p,
                                                    const float* __restrict__ cW2, unsigned short* __restrict__ cW2p,
                                                    const float* __restrict__ cW3, unsigned short* __restrict__ cW3p) {
    int gid = blockIdx.x * 256 + threadIdx.x;
    int lane = threadIdx.x & 63;
    int n = blockIdx.x * 4 + (threadIdx.x >> 6);
    if (n < N) enc_node(x, encW, encb, encls, enclb, h, n, lane);
    if (gid < E) atomicAdd(&deg[dst[gid]], 1);
    if (gid < NL * 2 * 16 * 8 * 64) repack_attn_one(Wl, Wr, Wp, gid);
    if (gid < 16 * 8 * 64) repack_gen_one(cW1, cW1p, D, D, 8, gid);
    if (gid < 8 * 8 * 64)  repack_gen_one(cW2, cW2p, D, 128, 8, gid);
    if (gid < 13 * 4 * 64) repack_gen_one(cW3, cW3p, 128, MC, 4, gid);
}

// single-block scan. deg holds in-degree only; +1 accounts for the self loop.
__global__ __launch_bounds__(1024) void scan_k(const int* __restrict__ deg, int* __restrict__ row_ptr,
                                               int* __restrict__ fill, int N) {
    __shared__ int sd[1024];
    int t = threadIdx.x;
    int chunk = (N + 1023) >> 10;
    int lo = t * chunk, hi = min(lo + chunk, N);
    int s = 0;
    for (int i = lo; i < hi; i++) s += deg[i] + 1;
    sd[t] = s;
    __syncthreads();
    for (int off = 1; off < 1024; off <<= 1) {
        int v = (t >= off) ? sd[t - off] : 0;
        __syncthreads();
        sd[t] += v;
        __syncthreads();
    }
    int run = (t > 0) ? sd[t - 1] : 0;
    for (int i = lo; i < hi; i++) {
        row_ptr[i] = run; fill[i] = run;
        run += deg[i] + 1;
    }
    if (t == 1023) row_ptr[N] = sd[1023];
}

// scatter + layer-0 GEMM
__global__ __launch_bounds__(256) void scatter_gemm0_k(const int* __restrict__ src, const int* __restrict__ dst,
                                                       int* __restrict__ fill, int* __restrict__ col, int E, int N,
                                                       const float* __restrict__ h,
                                                       const unsigned short* __restrict__ WpL,
                                                       const unsigned short* __restrict__ WpR,
                                                       const float* __restrict__ bl, const float* __restrict__ br,
                                                       unsigned short* __restrict__ xl, unsigned short* __restrict__ xr) {
    __shared__ unsigned short As[16][264];
    int T = threadIdx.x;
    int tt = blockIdx.x;
    int ntiles = (N + 15) >> 4;
    if (tt < ntiles) {
        int nb = tt * 16;
#pragma unroll
        for (int r = 0; r < 16; r++) {
            int row = nb + r;
            float v = (row < N) ? h[(size_t)row * D + T] : 0.f;
            As[r][T] = f2bf(v);
        }
        __syncthreads();
        gemm_core(As, WpL, WpR, bl, br, xl, xr, N, nb, T);
    }
    for (int e = blockIdx.x * 256 + T; e < E + N; e += gridDim.x * 256) {
        if (e < E) {
            int p = atomicAdd(&fill[dst[e]], 1);
            col[p] = src[e];
        } else {
            int n = e - E;
            int p = atomicAdd(&fill[n], 1);
            col[p] = n;
        }
    }
}

// attention-only kernel: 256 threads = 4 waves, ONE node per wave, no LDS, no barriers.
// TWO edges per wave-step: each half-wave (32 lanes x 16B = 512B) gathers one full
// xl row; lane holds 8 channels. Per edge vs the 1-edge/step form: half the loop and
// address overhead, 2 shfls instead of 3 for the z-reduce (head = 4 lanes), half the
// __expf count, and 8 edges in flight at depth-4. No running-max (order-free sums),
// which also legalizes the layer-0 in-register row sort (ascending sweep, L2-friendly).
__global__ __launch_bounds__(256, 4) void attn_k(const unsigned short* __restrict__ xl_in,
                                                 const unsigned short* __restrict__ xr_in,
                                                 const int* __restrict__ row_ptr, int* __restrict__ col,
                                                 const float* __restrict__ att, const float* __restrict__ gb,
                                                 const float* __restrict__ gls, const float* __restrict__ glb,
                                                 float* __restrict__ h, int layer, int N) {
    int T = threadIdx.x;
    int lane = T & 63, wv = T >> 6;
    int n = blockIdx.x * 4 + wv;
    if (n >= N) return;
    int half = lane >> 5, sub = lane & 31, c8 = sub * 8;
    int beg = row_ptr[n], deg = row_ptr[n + 1] - beg;
    int myc = col[beg + min(lane, deg - 1)];
    if (layer == 0 && deg <= 64) {
        // wave-level bitonic sort of this row's columns (each wave owns its row)
        int key = (lane < deg) ? myc : 0x7FFFFFFF;
#pragma unroll
        for (int k = 2; k <= 64; k <<= 1) {
#pragma unroll
            for (int j = k >> 1; j > 0; j >>= 1) {
                int other = __shfl_xor(key, j);
                bool up = ((lane & k) == 0);
                key = ((((lane & j) == 0) == up) ? min(key, other) : max(key, other));
            }
        }
        if (lane < deg) col[beg + lane] = key;
        myc = key;
    }
    float xrv[8], av[8], acc[8] = {0.f, 0.f, 0.f, 0.f, 0.f, 0.f, 0.f, 0.f};
    {
        const unsigned short* xp = &xr_in[(size_t)n * D + c8];
        ushort4 r0 = *(const ushort4*)xp;
        ushort4 r1 = *(const ushort4*)(xp + 4);
        xrv[0] = bf2f(r0.x); xrv[1] = bf2f(r0.y); xrv[2] = bf2f(r0.z); xrv[3] = bf2f(r0.w);
        xrv[4] = bf2f(r1.x); xrv[5] = bf2f(r1.y); xrv[6] = bf2f(r1.z); xrv[7] = bf2f(r1.w);
        float4 a0 = *(const float4*)&att[c8];
        float4 a1 = *(const float4*)&att[c8 + 4];
        av[0] = a0.x; av[1] = a0.y; av[2] = a0.z; av[3] = a0.w;
        av[4] = a1.x; av[5] = a1.y; av[6] = a1.z; av[7] = a1.w;
    }
    float l = 0.f;
    auto loadp = [&](int i) -> bfrag {
        int eidx = 2 * i + half;
        if (eidx < deg) {
            int s = (eidx < 64) ? __shfl(myc, eidx) : col[beg + eidx];
            return *(const bfrag*)&xl_in[(size_t)s * D + c8];
        }
        bfrag z = {0, 0, 0, 0, 0, 0, 0, 0};
        return z;
    };
    auto step = [&](bfrag x8, int i) {
        float xlv[8];
#pragma unroll
        for (int j = 0; j < 8; j++) xlv[j] = bf2f((unsigned short)x8[j]);
        float z = 0.f;
#pragma unroll
        for (int j = 0; j < 8; j++) {
            float s = xlv[j] + xrv[j];
            s = s > 0.f ? s : NEG * s;
            z = fmaf(av[j], s, z);
        }
        z += __shfl_xor(z, 1);
        z += __shfl_xor(z, 2);
        float p = __expf(z);
        p = (2 * i + half < deg) ? p : 0.f;
        l += p;
#pragma unroll
        for (int j = 0; j < 8; j++) acc[j] = fmaf(p, xlv[j], acc[j]);
    };
    int S = (deg + 1) >> 1;   // edge pairs
    bfrag b0 = loadp(0), b1 = loadp(1), b2 = loadp(2), b3 = loadp(3);
    int i = 0;
    for (; i + 4 <= S; i += 4) {
        bfrag q0 = loadp(i + 4), q1 = loadp(i + 5), q2 = loadp(i + 6), q3 = loadp(i + 7);
        step(b0, i); step(b1, i + 1); step(b2, i + 2); step(b3, i + 3);
        b0 = q0; b1 = q1; b2 = q2; b3 = q3;
    }
    if (i     < S) step(b0, i);
    if (i + 1 < S) step(b1, i + 1);
    if (i + 2 < S) step(b2, i + 2);
    // combine the two half-wave accumulations
    l += __shfl_xor(l, 32);
#pragma unroll
    for (int j = 0; j < 8; j++) acc[j] += __shfl_xor(acc[j], 32);
    float rl = 1.f / l;
    float o[8];
    {
        float4 g0 = *(const float4*)&gb[c8];
        float4 g1 = *(const float4*)&gb[c8 + 4];
        float gv[8] = {g0.x, g0.y, g0.z, g0.w, g1.x, g1.y, g1.z, g1.w};
#pragma unroll
        for (int j = 0; j < 8; j++) o[j] = acc[j] * rl + gv[j];
    }
    // LayerNorm over 256 channels: each half-wave spans all channels (32 lanes x 8)
    float s = 0.f;
#pragma unroll
    for (int j = 0; j < 8; j++) s += o[j];
#pragma unroll
    for (int msk = 1; msk <= 16; msk <<= 1) s += __shfl_xor(s, msk);
    float mu = s * (1.f / D);
    float dv[8];
    float v2 = 0.f;
#pragma unroll
    for (int j = 0; j < 8; j++) { dv[j] = o[j] - mu; v2 = fmaf(dv[j], dv[j], v2); }
#pragma unroll
    for (int msk = 1; msk <= 16; msk <<= 1) v2 += __shfl_xor(v2, msk);
    float rstd = rsqrtf(v2 * (1.f / D) + 1e-5f);
    if (half == 0) {
        float4 s0 = *(const float4*)&gls[c8];
        float4 s1 = *(const float4*)&gls[c8 + 4];
        float4 t0 = *(const float4*)&glb[c8];
        float4 t1 = *(const float4*)&glb[c8 + 4];
        float sv[8] = {s0.x, s0.y, s0.z, s0.w, s1.x, s1.y, s1.z, s1.w};
        float tv[8] = {t0.x, t0.y, t0.z, t0.w, t1.x, t1.y, t1.z, t1.w};
        float out[8];
#pragma unroll
        for (int j = 0; j < 8; j++) {
            float y = dv[j] * rstd * sv[j] + tv[j];
            out[j] = y > 0.f ? y : expm1f(y);
        }
        if (layer > 0) {
            float4 p0 = *(const float4*)&h[(size_t)n * D + c8];
            float4 p1 = *(const float4*)&h[(size_t)n * D + c8 + 4];
            out[0] += p0.x; out[1] += p0.y; out[2] += p0.z; out[3] += p0.w;
            out[4] += p1.x; out[5] += p1.y; out[6] += p1.z; out[7] += p1.w;
        }
        *(float4*)&h[(size_t)n * D + c8]     = make_float4(out[0], out[1], out[2], out[3]);
        *(float4*)&h[(size_t)n * D + c8 + 4] = make_float4(out[4], out[5], out[6], out[7]);
    }
}

// GEMM-only kernel: reads h (f32), produces xl/xr (bf16) for the NEXT layer.
__global__ __launch_bounds__(256, 4) void gemm_lr_k(const float* __restrict__ h,
                                                    const unsigned short* __restrict__ WpL,
                                                    const unsigned short* __restrict__ WpR,
                                                    const float* __restrict__ bl, const float* __restrict__ br,
                                                    unsigned short* __restrict__ xl, unsigned short* __restrict__ xr,
                                                    int N) {
    __shared__ unsigned short As[16][264];
    int T = threadIdx.x;
    int nb = blockIdx.x * 16;
#pragma unroll
    for (int r = 0; r < 16; r++) {
        int row = nb + r;
        float v = (row < N) ? h[(size_t)row * D + T] : 0.f;
        As[r][T] = f2bf(v);
    }
    __syncthreads();
    gemm_core(As, WpL, WpR, bl, br, xl, xr, N, nb, T);
}

// color-head MLP (MFMA), reads h: 1024 threads, 16 nodes/block.
__global__ __launch_bounds__(1024) void colorhead_k(const float* __restrict__ h, int N,
                                                    const unsigned short* __restrict__ W1p, const float* __restrict__ b1,
                                                    const unsigned short* __restrict__ W2p, const float* __restrict__ b2,
                                                    const unsigned short* __restrict__ W3p, const float* __restrict__ b3,
                                                    float* __restrict__ out) {
    __shared__ unsigned short As[16][264];
    __shared__ unsigned short Zs[16][264];
    int T = threadIdx.x;
    int lane = T & 63, wv = T >> 6;
    int nb = blockIdx.x * 16;
    int c4 = lane * 4;
    int n = nb + wv;
    if (n < N) {
        float4 v = *(const float4*)&h[(size_t)n * D + c4];
        As[wv][c4 + 0] = f2bf(v.x);
        As[wv][c4 + 1] = f2bf(v.y);
        As[wv][c4 + 2] = f2bf(v.z);
        As[wv][c4 + 3] = f2bf(v.w);
    } else {
        As[wv][c4 + 0] = 0; As[wv][c4 + 1] = 0; As[wv][c4 + 2] = 0; As[wv][c4 + 3] = 0;
    }
    __syncthreads();
    int m = lane & 15, q = lane >> 4;
    {
        float bv = b1[wv * 16 + m];
        f32x4 acc = (f32x4){bv, bv, bv, bv};
#pragma unroll
        for (int ks = 0; ks < 8; ks++) {
            bfrag af = *(const bfrag*)&As[m][ks * 32 + q * 8];
            bfrag bf = *(const bfrag*)&W1p[(((size_t)wv * 8 + ks) * 64 + lane) * 8];
            acc = __builtin_amdgcn_mfma_f32_16x16x32_bf16(af, bf, acc, 0, 0, 0);
        }
        int colg = wv * 16 + m;
#pragma unroll
        for (int reg = 0; reg < 4; reg++)
            Zs[q * 4 + reg][colg] = f2bf(fmaxf(acc[reg], 0.f));
    }
    __syncthreads();
    if (wv < 8) {
        float bv = b2[wv * 16 + m];
        f32x4 acc = (f32x4){bv, bv, bv, bv};
#pragma unroll
        for (int ks = 0; ks < 8; ks++) {
            bfrag af = *(const bfrag*)&Zs[m][ks * 32 + q * 8];
            bfrag bf = *(const bfrag*)&W2p[(((size_t)wv * 8 + ks) * 64 + lane) * 8];
            acc = __builtin_amdgcn_mfma_f32_16x16x32_bf16(af, bf, acc, 0, 0, 0);
        }
        int colg = wv * 16 + m;
#pragma unroll
        for (int reg = 0; reg < 4; reg++)
            As[q * 4 + reg][colg] = f2bf(fmaxf(acc[reg], 0.f));
    }
    __syncthreads();
    if (wv < 13) {
        int colg = wv * 16 + m;
        float bv = (colg < MC) ? b3[colg] : 0.f;
        f32x4 acc = (f32x4){bv, bv, bv, bv};
#pragma unroll
        for (int ks = 0; ks < 4; ks++) {
            bfrag af = *(const bfrag*)&As[m][ks * 32 + q * 8];
            bfrag bf = *(const bfrag*)&W3p[(((size_t)wv * 4 + ks) * 64 + lane) * 8];
            acc = __builtin_amdgcn_mfma_f32_16x16x32_bf16(af, bf, acc, 0, 0, 0);
        }
#pragma unroll
        for (int reg = 0; reg < 4; reg++) {
            int row = nb + q * 4 + reg;
            if (row < N && colg < MC) out[(size_t)row * MC + colg] = acc[reg];
        }
    }
}

// pooling stage 1 (256 blocks: 16 graphs x 16 slices)
__global__ __launch_bounds__(256) void pool_k(const float* __restrict__ h, const int* __restrict__ batch,
                                              float* __restrict__ psum, float* __restrict__ pmax,
                                              int* __restrict__ cnt, int N) {
    int b = blockIdx.x;
    int sl = blockIdx.y;
    int c = threadIdx.x;
    int lo = 0, hi = N;
    while (lo < hi) { int mid = (lo + hi) >> 1; if (batch[mid] < b) lo = mid + 1; else hi = mid; }
    int s0 = lo;
    lo = 0; hi = N;
    while (lo < hi) { int mid = (lo + hi) >> 1; if (batch[mid] < b + 1) lo = mid + 1; else hi = mid; }
    int s1 = lo;
    int len = s1 - s0;
    int chunk = (len + PS - 1) / PS;
    int n0 = s0 + sl * chunk;
    int n1 = min(n0 + chunk, s1);
    float sum = 0.f, mx = -3.0e38f;
    for (int n = n0; n < n1; n++) {
        float v = h[(size_t)n * D + c];
        sum += v;
        mx = fmaxf(mx, v);
    }
    psum[(size_t)(b * PS + sl) * D + c] = sum;
    pmax[(size_t)(b * PS + sl) * D + c] = mx;
    if (c == 0 && sl == 0) cnt[b] = len;
}

// graph heads
__global__ __launch_bounds__(256) void heads_k(const float* __restrict__ psum, const float* __restrict__ pmax,
                                               const int* __restrict__ cnt,
                                               const float* __restrict__ chW1, const float* __restrict__ chb1,
                                               const float* __restrict__ chW2, const float* __restrict__ chb2,
                                               const float* __restrict__ chW3, const float* __restrict__ chb3,
                                               const float* __restrict__ tW1, const float* __restrict__ tb1,
                                               const float* __restrict__ tW2, const float* __restrict__ tb2,
                                               const float* __restrict__ dW1, const float* __restrict__ db1,
                                               const float* __restrict__ dW2, const float* __restrict__ db2,
                                               float* __restrict__ out_ch, float* __restrict__ out_t,
                                               float* __restrict__ out_d) {
    int b = blockIdx.x, sec = blockIdx.y, t = threadIdx.x;
    __shared__ float g[2 * D];
    __shared__ float z1[D];
    __shared__ float z2[128];
    float sum = 0.f, mx = -3.0e38f;
#pragma unroll
    for (int sl = 0; sl < PS; sl++) {
        sum += psum[(size_t)(b * PS + sl) * D + t];
        mx = fmaxf(mx, pmax[(size_t)(b * PS + sl) * D + t]);
    }
    int cn = cnt[b];
    float c = fmaxf((float)cn, 1.f);
    g[t] = sum / c;
    g[D + t] = (cn > 0) ? mx : 0.f;
    __syncthreads();
    if (sec == 0) {
        z1[t] = fmaxf(chb1[t] + dot_ilp(g, chW1, 2 * D, D, t), 0.f);
        __syncthreads();
        if (t < 128) z2[t] = fmaxf(chb2[t] + dot_ilp(z1, chW2, D, 128, t), 0.f);
        __syncthreads();
        if (t < MC) out_ch[b * MC + t] = chb3[t] + dot_ilp(z2, chW3, 128, MC, t);
    } else if (sec == 1) {
        if (t < 128) z1[t] = fmaxf(tb1[t] + dot_ilp(g, tW1, 2 * D, 128, t), 0.f);
        __syncthreads();
        if (t < NT) out_t[b * NT + t] = tb2[t] + dot_ilp(z1, tW2, 128, NT, t);
    } else {
        if (t < 64) z1[t] = fmaxf(db1[t] + dot_ilp(g, dW1, 2 * D, 64, t), 0.f);
        __syncthreads();
        if (t == 0) {
            float a = db2[0] + dot_ilp(z1, dW2, 64, 1, 0);
            out_d[b] = 100.f / (1.f + __expf(-a));
        }
    }
}

// ----------------------------------------------------------------
extern "C" void kernel_launch(void* const* d_in, const int* in_sizes, int n_in,
                              void* d_out, int out_size, void* d_ws, size_t ws_size,
                              hipStream_t stream) {
    const float* x     = (const float*)d_in[0];
    const int*   ei    = (const int*)d_in[1];
    const int*   batch = (const int*)d_in[2];
    const float* encW  = (const float*)d_in[3];
    const float* encb  = (const float*)d_in[4];
    const float* encls = (const float*)d_in[5];
    const float* enclb = (const float*)d_in[6];
    const float* Wl    = (const float*)d_in[7];
    const float* bl    = (const float*)d_in[8];
    const float* Wr    = (const float*)d_in[9];
    const float* br    = (const float*)d_in[10];
    const float* att   = (const float*)d_in[11];
    const float* gb    = (const float*)d_in[12];
    const float* gls   = (const float*)d_in[13];
    const float* glb   = (const float*)d_in[14];
    const float* cW1   = (const float*)d_in[15];
    const float* cb1   = (const float*)d_in[16];
    const float* cW2   = (const float*)d_in[17];
    const float* cb2   = (const float*)d_in[18];
    const float* cW3   = (const float*)d_in[19];
    const float* cb3   = (const float*)d_in[20];
    const float* chW1  = (const float*)d_in[21];
    const float* chb1  = (const float*)d_in[22];
    const float* chW2  = (const float*)d_in[23];
    const float* chb2  = (const float*)d_in[24];
    const float* chW3  = (const float*)d_in[25];
    const float* chb3  = (const float*)d_in[26];
    const float* tW1   = (const float*)d_in[27];
    const float* tb1   = (const float*)d_in[28];
    const float* tW2   = (const float*)d_in[29];
    const float* tb2   = (const float*)d_in[30];
    const float* dW1   = (const float*)d_in[31];
    const float* db1   = (const float*)d_in[32];
    const float* dW2   = (const float*)d_in[33];
    const float* db2   = (const float*)d_in[34];

    const int N = in_sizes[0] / DIN;
    const int E = in_sizes[1] / 2;
    const int* esrc = ei;
    const int* edst = ei + E;

    char* p = (char*)d_ws;
    auto carve = [&](size_t bytes) { char* r = p; p += (bytes + 255) & ~(size_t)255; return r; };
    int*            row_ptr = (int*)carve((size_t)(N + 1) * 4);
    int*            fill    = (int*)carve((size_t)N * 4);
    int*            deg     = (int*)carve((size_t)N * 4);
    int*            cnt     = (int*)carve((size_t)BG * 4);
    float*          psum    = (float*)carve((size_t)BG * PS * D * 4);
    float*          pmax    = (float*)carve((size_t)BG * PS * D * 4);
    int*            col     = (int*)carve((size_t)(E + N) * 4);
    unsigned short* Wp      = (unsigned short*)carve((size_t)NL * 2 * 65536 * 2);
    unsigned short* cW1p    = (unsigned short*)carve((size_t)16 * 8 * 64 * 8 * 2);
    unsigned short* cW2p    = (unsigned short*)carve((size_t)8 * 8 * 64 * 8 * 2);
    unsigned short* cW3p    = (unsigned short*)carve((size_t)13 * 4 * 64 * 8 * 2);
    float*          h       = (float*)carve((size_t)N * D * 4);
    unsigned short* xlA     = (unsigned short*)carve((size_t)N * D * 2);
    unsigned short* xrA     = (unsigned short*)carve((size_t)N * D * 2);
    unsigned short* xlB     = (unsigned short*)carve((size_t)N * D * 2);
    unsigned short* xrB     = (unsigned short*)carve((size_t)N * D * 2);
    (void)ws_size; (void)n_in; (void)out_size;

    const int ntiles16 = (N + 15) / 16;
    const int nblk4    = (N + 3) / 4;
    const int sblocks  = max(ntiles16, (E + N + 255) / 256);
    const int fblocks  = max((N + 3) / 4, max((E + 255) / 256, 384));

    hipMemsetAsync(deg, 0, (size_t)N * 4, stream);
    fused_init_k<<<fblocks, 256, 0, stream>>>(x, encW, encb, encls, enclb, h, N,
                                              edst, deg, E, Wl, Wr, Wp,
                                              cW1, cW1p, cW2, cW2p, cW3, cW3p);
    scan_k<<<1, 1024, 0, stream>>>(deg, row_ptr, fill, N);
    scatter_gemm0_k<<<sblocks, 256, 0, stream>>>(esrc, edst, fill, col, E, N, h,
                                                 Wp + 0, Wp + (size_t)65536,
                                                 bl + 0, br + 0, xlA, xrA);
    for (int l = 0; l < NL - 1; l++) {
        const unsigned short* xin_l = (l & 1) ? xlB : xlA;
        const unsigned short* xin_r = (l & 1) ? xrB : xrA;
        unsigned short* xout_l = (l & 1) ? xlA : xlB;
        unsigned short* xout_r = (l & 1) ? xrA : xrB;
        attn_k<<<nblk4, 256, 0, stream>>>(xin_l, xin_r, row_ptr, col, att + l * NH * NC,
                                          gb + l * D, gls + l * D, glb + l * D, h, l, N);
        gemm_lr_k<<<ntiles16, 256, 0, stream>>>(h,
                                                Wp + (size_t)((l + 1) * 2 + 0) * 65536,
                                                Wp + (size_t)((l + 1) * 2 + 1) * 65536,
                                                bl + (l + 1) * D, br + (l + 1) * D, xout_l, xout_r, N);
    }
    float* out = (float*)d_out;
    attn_k<<<nblk4, 256, 0, stream>>>(xlB, xrB, row_ptr, col, att + (NL - 1) * NH * NC,
                                      gb + (NL - 1) * D, gls + (NL - 1) * D, glb + (NL - 1) * D,
                                      h, NL - 1, N);
    colorhead_k<<<ntiles16, 1024, 0, stream>>>(h, N, cW1p, cb1, cW2p, cb2, cW3p, cb3, out);
    pool_k<<<dim3(BG, PS), 256, 0, stream>>>(h, batch, psum, pmax, cnt, N);
    heads_k<<<dim3(BG, 3), 256, 0, stream>>>(psum, pmax, cnt, chW1, chb1, chW2, chb2, chW3, chb3,
                                             tW1, tb1, tW2, tb2, dW1, db1, dW2, db2,
                                             out + (size_t)N * MC,
                                             out + (size_t)N * MC + BG * MC,
                                             out + (size_t)N * MC + BG * MC + BG * NT);
}